// Round 1
// baseline (123.533 us; speedup 1.0000x reference)
//
#include <hip/hip_runtime.h>
#include <math.h>

// Affine warp augmentation (kornia-style warp_affine, bilinear, zeros padding,
// align_corners pixel coords). B=128, C=3, H=W=256, fp32.

#ifndef AUG_ANG
#define AUG_ANG 0.34906585039886590  // deg2rad(20)
#endif
#define AUG_MAX_T 6.0

// One thread per batch element: build the 2x3 affine matrix exactly as the
// reference does, invert the 2x2 part, store {i00,i01,i10,i11,T13,T23}.
__global__ void TCR_params_kernel(const float* __restrict__ rnd,
                                  float* __restrict__ p,
                                  int B, int W, int H) {
    int b = blockIdx.x * blockDim.x + threadIdx.x;
    if (b >= B) return;
    double r01 = (double)rnd[b];
    double tx = 2.0 * AUG_MAX_T * r01 - AUG_MAX_T;
    double ty = tx;                       // same random tensor for all params
    double r  = 2.0 * AUG_ANG * r01 - AUG_ANG;
    double z  = 1.0;                      // MAX_Z == MIN_Z == 1
    double hx = r, hy = r;
    double a  = hx - r;                   // == 0 numerically, keep general form
    double bb = hy + r;
    double cos_hx = cos(hx), cos_hy = cos(hy);
    double ca = cos(a),  sa = sin(a);
    double cb = cos(bb), sb = sin(bb);
    double T11 = z * ca / cos_hx;
    double T12 = z * sa / cos_hx;
    double T13 = ((double)W * cos_hx - (double)W * z * ca + 2.0 * tx * z * ca
                  - (double)H * z * sa + 2.0 * ty * z * sa) / (2.0 * cos_hx);
    double T21 = z * sb / cos_hy;
    double T22 = z * cb / cos_hy;
    double T23 = ((double)H * cos_hy - (double)W * z * cb + 2.0 * ty * z * cb
                  - (double)W * z * sb + 2.0 * tx * z * sb) / (2.0 * cos_hy);
    double det = T11 * T22 - T12 * T21;
    p[b * 6 + 0] = (float)( T22 / det);
    p[b * 6 + 1] = (float)(-T12 / det);
    p[b * 6 + 2] = (float)(-T21 / det);
    p[b * 6 + 3] = (float)( T11 / det);
    p[b * 6 + 4] = (float)T13;
    p[b * 6 + 5] = (float)T23;
}

// One thread per (b, y, x); loops over C channels.
// Stores coalesced (lane -> x). Params are block-uniform -> scalar loads.
__global__ __launch_bounds__(256) void TCR_warp_kernel(
        const float* __restrict__ img, const float* __restrict__ p,
        float* __restrict__ out, int C, int H, int W) {
    const int x = blockIdx.x * blockDim.x + threadIdx.x;
    const int y = blockIdx.y;
    const int b = blockIdx.z;
    if (x >= W) return;

    const float i00 = p[b * 6 + 0];
    const float i01 = p[b * 6 + 1];
    const float i10 = p[b * 6 + 2];
    const float i11 = p[b * 6 + 3];
    const float T13 = p[b * 6 + 4];
    const float T23 = p[b * 6 + 5];

    const float dx = (float)x - T13;
    const float dy = (float)y - T23;
    const float sx = i00 * dx + i01 * dy;
    const float sy = i10 * dx + i11 * dy;

    const float x0f = floorf(sx);
    const float y0f = floorf(sy);
    const float wx = sx - x0f;
    const float wy = sy - y0f;
    const int x0 = (int)x0f, y0 = (int)y0f;
    const int x1 = x0 + 1,   y1 = y0 + 1;

    const bool vx0 = (x0 >= 0) & (x0 < W);
    const bool vx1 = (x1 >= 0) & (x1 < W);
    const bool vy0 = (y0 >= 0) & (y0 < H);
    const bool vy1 = (y1 >= 0) & (y1 < H);
    const int xc0 = min(max(x0, 0), W - 1);
    const int xc1 = min(max(x1, 0), W - 1);
    const int yc0 = min(max(y0, 0), H - 1);
    const int yc1 = min(max(y1, 0), H - 1);

    const float w00 = (1.0f - wx) * (1.0f - wy);
    const float w01 = wx * (1.0f - wy);
    const float w10 = (1.0f - wx) * wy;
    const float w11 = wx * wy;

    const size_t plane = (size_t)H * W;
    const size_t base  = (size_t)b * C * plane;
    const size_t o00 = (size_t)yc0 * W + xc0;
    const size_t o01 = (size_t)yc0 * W + xc1;
    const size_t o10 = (size_t)yc1 * W + xc0;
    const size_t o11 = (size_t)yc1 * W + xc1;
    const size_t oo  = (size_t)y * W + x;

    #pragma unroll
    for (int c = 0; c < 3; ++c) {
        const float* pl = img + base + (size_t)c * plane;
        float v00 = (vx0 && vy0) ? pl[o00] : 0.0f;
        float v01 = (vx1 && vy0) ? pl[o01] : 0.0f;
        float v10 = (vx0 && vy1) ? pl[o10] : 0.0f;
        float v11 = (vx1 && vy1) ? pl[o11] : 0.0f;
        out[base + (size_t)c * plane + oo] =
            v00 * w00 + v01 * w01 + v10 * w10 + v11 * w11;
    }
}

extern "C" void kernel_launch(void* const* d_in, const int* in_sizes, int n_in,
                              void* d_out, int out_size, void* d_ws, size_t ws_size,
                              hipStream_t stream) {
    const float* img = (const float*)d_in[0];
    const float* rnd = (const float*)d_in[1];
    float* out = (float*)d_out;
    float* params = (float*)d_ws;

    const int B = in_sizes[1];            // 128
    const int C = 3;
    const int total = in_sizes[0];        // B*C*H*W
    const int HW = total / (B * C);       // 65536
    int W = 256;                          // square images
    while (W * W > HW) W >>= 1;
    const int H = HW / W;

    TCR_params_kernel<<<(B + 127) / 128, 128, 0, stream>>>(rnd, params, B, W, H);

    dim3 grid((W + 255) / 256, H, B);
    TCR_warp_kernel<<<grid, 256, 0, stream>>>(img, params, out, C, H, W);
}

// Round 2
// 111.087 us; speedup vs baseline: 1.1120x; 1.1120x over previous
//
#include <hip/hip_runtime.h>
#include <math.h>

// Affine warp augmentation (kornia-style warp_affine, bilinear, zeros padding,
// align_corners pixel coords). B=128, C=3, H=W=256, fp32.
//
// R2: 256x8 output tile per block (8 y-rows per thread) for gather-line reuse,
// XCD-bijective block swizzle (all y-tiles of one image -> same XCD L2),
// nontemporal output stores (write stream must not evict gather lines).

#define AUG_ANG 0.34906585039886590  // deg2rad(20)
#define AUG_MAX_T 6.0
#define TY 8

// One thread per batch element: build the 2x3 affine matrix exactly as the
// reference does, invert the 2x2 part, store {i00,i01,i10,i11,T13,T23}.
__global__ void TCR_params_kernel(const float* __restrict__ rnd,
                                  float* __restrict__ p,
                                  int B, int W, int H) {
    int b = blockIdx.x * blockDim.x + threadIdx.x;
    if (b >= B) return;
    double r01 = (double)rnd[b];
    double tx = 2.0 * AUG_MAX_T * r01 - AUG_MAX_T;
    double ty = tx;                       // same random tensor for all params
    double r  = 2.0 * AUG_ANG * r01 - AUG_ANG;
    double z  = 1.0;                      // MAX_Z == MIN_Z == 1
    double hx = r, hy = r;
    double a  = hx - r;
    double bb = hy + r;
    double cos_hx = cos(hx), cos_hy = cos(hy);
    double ca = cos(a),  sa = sin(a);
    double cb = cos(bb), sb = sin(bb);
    double T11 = z * ca / cos_hx;
    double T12 = z * sa / cos_hx;
    double T13 = ((double)W * cos_hx - (double)W * z * ca + 2.0 * tx * z * ca
                  - (double)H * z * sa + 2.0 * ty * z * sa) / (2.0 * cos_hx);
    double T21 = z * sb / cos_hy;
    double T22 = z * cb / cos_hy;
    double T23 = ((double)H * cos_hy - (double)W * z * cb + 2.0 * ty * z * cb
                  - (double)W * z * sb + 2.0 * tx * z * sb) / (2.0 * cos_hy);
    double det = T11 * T22 - T12 * T21;
    p[b * 6 + 0] = (float)( T22 / det);
    p[b * 6 + 1] = (float)(-T12 / det);
    p[b * 6 + 2] = (float)(-T21 / det);
    p[b * 6 + 3] = (float)( T11 / det);
    p[b * 6 + 4] = (float)T13;
    p[b * 6 + 5] = (float)T23;
}

// Block = 256 threads = one full x-row span; each thread does TY consecutive
// y rows (256xTY tile). Gathers for adjacent y reuse the same source lines in
// L1/L2. Swizzle keeps every y-tile of an image on one XCD's L2.
__global__ __launch_bounds__(256) void TCR_warp_kernel(
        const float* __restrict__ img, const float* __restrict__ p,
        float* __restrict__ out, int H, int W, int nYT, int useSwz) {
    int i = (int)blockIdx.x;
    int b, yt;
    if (useSwz) {
        // round-robin heuristic: linear block i -> XCD i%8. Keep i%8 constant
        // per image so all of an image's tiles share one L2.
        int xcd = i & 7;
        int r   = i >> 3;
        b  = xcd + 8 * (r / nYT);
        yt = r % nYT;
    } else {
        b  = i / nYT;
        yt = i % nYT;
    }
    const int x = (int)threadIdx.x;
    if (x >= W) return;

    const float i00 = p[b * 6 + 0];
    const float i01 = p[b * 6 + 1];
    const float i10 = p[b * 6 + 2];
    const float i11 = p[b * 6 + 3];
    const float T13 = p[b * 6 + 4];
    const float T23 = p[b * 6 + 5];

    const size_t plane = (size_t)H * W;
    const size_t base  = (size_t)b * 3 * plane;
    const float dx = (float)x - T13;
    const float sxb = i00 * dx;
    const float syb = i10 * dx;
    const int yrow0 = yt * TY;

    #pragma unroll
    for (int yy = 0; yy < TY; ++yy) {
        const int y = yrow0 + yy;
        if (y >= H) break;
        const float dy = (float)y - T23;
        const float sx = sxb + i01 * dy;
        const float sy = syb + i11 * dy;

        const float x0f = floorf(sx);
        const float y0f = floorf(sy);
        const float wx = sx - x0f;
        const float wy = sy - y0f;
        const int x0 = (int)x0f, y0 = (int)y0f;
        const int x1 = x0 + 1,   y1 = y0 + 1;

        const bool vx0 = (unsigned)x0 < (unsigned)W;
        const bool vx1 = (unsigned)x1 < (unsigned)W;
        const bool vy0 = (unsigned)y0 < (unsigned)H;
        const bool vy1 = (unsigned)y1 < (unsigned)H;
        const int xc0 = min(max(x0, 0), W - 1);
        const int xc1 = min(max(x1, 0), W - 1);
        const int yc0 = min(max(y0, 0), H - 1);
        const int yc1 = min(max(y1, 0), H - 1);

        const float w00 = (1.0f - wx) * (1.0f - wy);
        const float w01 = wx * (1.0f - wy);
        const float w10 = (1.0f - wx) * wy;
        const float w11 = wx * wy;

        const size_t o00 = (size_t)yc0 * W + xc0;
        const size_t o01 = (size_t)yc0 * W + xc1;
        const size_t o10 = (size_t)yc1 * W + xc0;
        const size_t o11 = (size_t)yc1 * W + xc1;
        const size_t oo  = (size_t)y * W + x;

        #pragma unroll
        for (int c = 0; c < 3; ++c) {
            const float* pl = img + base + (size_t)c * plane;
            float v00 = (vx0 && vy0) ? pl[o00] : 0.0f;
            float v01 = (vx1 && vy0) ? pl[o01] : 0.0f;
            float v10 = (vx0 && vy1) ? pl[o10] : 0.0f;
            float v11 = (vx1 && vy1) ? pl[o11] : 0.0f;
            float v = v00 * w00 + v01 * w01 + v10 * w10 + v11 * w11;
            __builtin_nontemporal_store(v, &out[base + (size_t)c * plane + oo]);
        }
    }
}

extern "C" void kernel_launch(void* const* d_in, const int* in_sizes, int n_in,
                              void* d_out, int out_size, void* d_ws, size_t ws_size,
                              hipStream_t stream) {
    const float* img = (const float*)d_in[0];
    const float* rnd = (const float*)d_in[1];
    float* out = (float*)d_out;
    float* params = (float*)d_ws;

    const int B = in_sizes[1];            // 128
    const int C = 3;
    const int total = in_sizes[0];        // B*C*H*W
    const int HW = total / (B * C);       // 65536
    int W = 256;                          // square images
    while (W * W > HW) W >>= 1;
    const int H = HW / W;

    TCR_params_kernel<<<(B + 127) / 128, 128, 0, stream>>>(rnd, params, B, W, H);

    const int nYT = (H + TY - 1) / TY;
    const int useSwz = (B % 8 == 0) ? 1 : 0;
    const int nBlocks = B * nYT;
    dim3 grid(nBlocks);
    dim3 block(W <= 256 ? ((W + 63) / 64) * 64 : 256);
    TCR_warp_kernel<<<grid, block, 0, stream>>>(img, params, out, H, W, nYT, useSwz);
}

// Round 4
// 100.668 us; speedup vs baseline: 1.2271x; 1.1035x over previous
//
#include <hip/hip_runtime.h>
#include <math.h>

// Affine warp augmentation (kornia-style warp_affine, bilinear, zeros padding,
// align_corners pixel coords). B=128, C=3, H=W=256, fp32.
//
// R4: LDS-staged gathers with ZERO-HALO. Each block owns a 64x64 output tile;
// the unclamped source bbox (<= 67 x 131 floats for |rot|<=20deg, where
// |i10|+i11 <= 2.016) is staged into LDS with 0.0 written for out-of-image
// positions. The bilinear inner loop then needs no validity masks or clamps:
// reads lds[iA], lds[iA+1], lds[iA+P], lds[iA+P+1] reproduce zeros-padding
// exactly. (R3 bug: assumed xc1==xc0+1, wrong at the left edge where
// x0=-1 -> clamp makes xc1==xc0==0.)

#define AUG_ANG 0.34906585039886590  // deg2rad(20)
#define AUG_MAX_T 6.0

#define TILE 64
#define PITCH 67       // LDS row pitch in floats (>= max ws = 67); odd
#define MAXROWS 134    // >= (0.789+1.227)*63 + 4 margin

// One thread per batch element: build the 2x3 affine matrix exactly as the
// reference does, invert the 2x2 part, store {i00,i01,i10,i11,T13,T23}.
__global__ void TCR_params_kernel(const float* __restrict__ rnd,
                                  float* __restrict__ p,
                                  int B, int W, int H) {
    int b = blockIdx.x * blockDim.x + threadIdx.x;
    if (b >= B) return;
    double r01 = (double)rnd[b];
    double tx = 2.0 * AUG_MAX_T * r01 - AUG_MAX_T;
    double ty = tx;                       // same random tensor for all params
    double r  = 2.0 * AUG_ANG * r01 - AUG_ANG;
    double z  = 1.0;                      // MAX_Z == MIN_Z == 1
    double hx = r, hy = r;
    double a  = hx - r;
    double bb = hy + r;
    double cos_hx = cos(hx), cos_hy = cos(hy);
    double ca = cos(a),  sa = sin(a);
    double cb = cos(bb), sb = sin(bb);
    double T11 = z * ca / cos_hx;
    double T12 = z * sa / cos_hx;
    double T13 = ((double)W * cos_hx - (double)W * z * ca + 2.0 * tx * z * ca
                  - (double)H * z * sa + 2.0 * ty * z * sa) / (2.0 * cos_hx);
    double T21 = z * sb / cos_hy;
    double T22 = z * cb / cos_hy;
    double T23 = ((double)H * cos_hy - (double)W * z * cb + 2.0 * ty * z * cb
                  - (double)W * z * sb + 2.0 * tx * z * sb) / (2.0 * cos_hy);
    double det = T11 * T22 - T12 * T21;
    p[b * 6 + 0] = (float)( T22 / det);
    p[b * 6 + 1] = (float)(-T12 / det);
    p[b * 6 + 2] = (float)(-T21 / det);
    p[b * 6 + 3] = (float)( T11 / det);
    p[b * 6 + 4] = (float)T13;
    p[b * 6 + 5] = (float)T23;
}

__global__ __launch_bounds__(256) void TCR_warp_kernel(
        const float* __restrict__ img, const float* __restrict__ p,
        float* __restrict__ out, int H, int W, int tilesX, int nT, int useSwz) {
    __shared__ float lds[MAXROWS * PITCH + 4];

    const int tid = (int)threadIdx.x;
    int i = (int)blockIdx.x;
    int b, t;
    if (useSwz) {   // keep all tiles of one image on one XCD's L2
        int xcd = i & 7;
        int r   = i >> 3;
        b = xcd + 8 * (r / nT);
        t = r % nT;
    } else {
        b = i / nT;
        t = i % nT;
    }
    const int tileY = t / tilesX, tileX = t - tileY * tilesX;
    const int tx0 = tileX * TILE, ty0 = tileY * TILE;
    const int tx1 = min(tx0 + TILE - 1, W - 1);
    const int ty1 = min(ty0 + TILE - 1, H - 1);

    const float i00 = p[b * 6 + 0];
    const float i01 = p[b * 6 + 1];
    const float i10 = p[b * 6 + 2];
    const float i11 = p[b * 6 + 3];
    const float T13 = p[b * 6 + 4];
    const float T23 = p[b * 6 + 5];

    // Unclamped source bbox from the 4 tile corners (affine => corners bound
    // the interior; +/-1 margin absorbs fp rounding). Zero-halo: positions
    // outside the image are staged as 0.0f.
    const float cx0 = (float)tx0 - T13, cx1 = (float)tx1 - T13;
    const float cy0 = (float)ty0 - T23, cy1 = (float)ty1 - T23;
    const float sxA = i00 * cx0 + i01 * cy0, sxB = i00 * cx1 + i01 * cy0;
    const float sxC = i00 * cx0 + i01 * cy1, sxD = i00 * cx1 + i01 * cy1;
    const float syA = i10 * cx0 + i11 * cy0, syB = i10 * cx1 + i11 * cy0;
    const float syC = i10 * cx0 + i11 * cy1, syD = i10 * cx1 + i11 * cy1;
    const float sxmin = fminf(fminf(sxA, sxB), fminf(sxC, sxD));
    const float sxmax = fmaxf(fmaxf(sxA, sxB), fmaxf(sxC, sxD));
    const float symin = fminf(fminf(syA, syB), fminf(syC, syD));
    const float symax = fmaxf(fmaxf(syA, syB), fmaxf(syC, syD));
    const int xs0 = (int)floorf(sxmin) - 1;
    const int ys0 = (int)floorf(symin) - 1;
    const int xs1 = min((int)floorf(sxmax) + 2, xs0 + PITCH - 1);   // defensive
    const int ys1 = min((int)floorf(symax) + 2, ys0 + MAXROWS - 1); // defensive
    const int ws = xs1 - xs0 + 1;
    const int hs = ys1 - ys0 + 1;
    const int total = hs * PITCH;

    const size_t plane = (size_t)H * W;
    const size_t base  = (size_t)b * 3 * plane;

    const int x = tx0 + (tid & 63);
    const int yrow = ty0 + (tid >> 6);     // + 4*k below
    const bool x_ok = (x <= tx1);
    const float dx = (float)x - T13;

    for (int c = 0; c < 3; ++c) {
        const float* pl = img + base + (size_t)c * plane;
        __syncthreads();   // previous channel's reads done before restage
        for (int j = tid; j < total; j += 256) {
            const int ry = j / PITCH;
            const int rx = j - ry * PITCH;
            const int gx = xs0 + rx;
            const int gy = ys0 + ry;
            float v = 0.0f;
            if ((rx < ws) & ((unsigned)gx < (unsigned)W) &
                ((unsigned)gy < (unsigned)H))
                v = pl[(size_t)gy * W + gx];
            lds[j] = v;
        }
        __syncthreads();

        if (!x_ok) continue;
        float* po = out + base + (size_t)c * plane;
        #pragma unroll
        for (int k = 0; k < TILE / 4; ++k) {
            const int y = yrow + 4 * k;
            if (y > ty1) break;            // wave-uniform
            const float dy = (float)y - T23;
            const float sx = i00 * dx + i01 * dy;
            const float sy = i10 * dx + i11 * dy;

            const float x0f = floorf(sx);
            const float y0f = floorf(sy);
            const float wx = sx - x0f;
            const float wy = sy - y0f;
            const int x0 = (int)x0f;
            const int y0 = (int)y0f;

            const int iA = (y0 - ys0) * PITCH + (x0 - xs0);
            const float v00 = lds[iA];
            const float v01 = lds[iA + 1];
            const float v10 = lds[iA + PITCH];
            const float v11 = lds[iA + PITCH + 1];

            const float w00 = (1.0f - wx) * (1.0f - wy);
            const float w01 = wx * (1.0f - wy);
            const float w10 = (1.0f - wx) * wy;
            const float w11 = wx * wy;

            const float v = v00 * w00 + v01 * w01 + v10 * w10 + v11 * w11;
            __builtin_nontemporal_store(v, &po[(size_t)y * W + x]);
        }
    }
}

extern "C" void kernel_launch(void* const* d_in, const int* in_sizes, int n_in,
                              void* d_out, int out_size, void* d_ws, size_t ws_size,
                              hipStream_t stream) {
    const float* img = (const float*)d_in[0];
    const float* rnd = (const float*)d_in[1];
    float* out = (float*)d_out;
    float* params = (float*)d_ws;

    const int B = in_sizes[1];            // 128
    const int C = 3;
    const int total = in_sizes[0];        // B*C*H*W
    const int HW = total / (B * C);       // 65536
    int W = 256;                          // square images
    while (W * W > HW) W >>= 1;
    const int H = HW / W;

    TCR_params_kernel<<<(B + 127) / 128, 128, 0, stream>>>(rnd, params, B, W, H);

    const int tilesX = (W + TILE - 1) / TILE;
    const int tilesY = (H + TILE - 1) / TILE;
    const int nT = tilesX * tilesY;
    const int useSwz = (B % 8 == 0) ? 1 : 0;
    dim3 grid(B * nT);
    TCR_warp_kernel<<<grid, 256, 0, stream>>>(img, params, out, H, W,
                                              tilesX, nT, useSwz);
}

// Round 5
// 45.538 us; speedup vs baseline: 2.7128x; 2.2106x over previous
//
#include <hip/hip_runtime.h>
#include <math.h>

// Affine warp augmentation (kornia-style warp_affine, bilinear, zeros padding,
// align_corners pixel coords). B=128, C=3, H=W=256, fp32.
//
// R5: tall tiles + one (b,c,tile) per block. Because T12==0 for this family,
// i01==0 -> sx depends only on x, so a 32-wide x 128-tall output tile has a
// source bbox of only <=36 x <=185 floats (i00=cos r <=1; |i10|<=0.789,
// i11<=1.227). LDS 26.5 KB -> 6 blocks/CU (~24 waves/CU) for latency hiding;
// one channel per block -> single __syncthreads; float2 zero-halo staging
// (clamped addresses, masked values). Gathers read LDS with no masks: halo
// zeros reproduce zeros-padding exactly (R4 scheme, kept).

#define AUG_ANG 0.34906585039886590  // deg2rad(20)
#define AUG_MAX_T 6.0

#define TW 32
#define TH 128
#define PITCH 36       // staged row width in floats (>= max ws 36), even
#define HPITCH (PITCH / 2)
#define MAXROWS 186    // >= |i10|*31 + i11*127 + 5

// One thread per batch element: build the 2x3 affine matrix exactly as the
// reference does, invert the 2x2 part, store {i00,i01,i10,i11,T13,T23}.
__global__ void TCR_params_kernel(const float* __restrict__ rnd,
                                  float* __restrict__ p,
                                  int B, int W, int H) {
    int b = blockIdx.x * blockDim.x + threadIdx.x;
    if (b >= B) return;
    double r01 = (double)rnd[b];
    double tx = 2.0 * AUG_MAX_T * r01 - AUG_MAX_T;
    double ty = tx;                       // same random tensor for all params
    double r  = 2.0 * AUG_ANG * r01 - AUG_ANG;
    double z  = 1.0;                      // MAX_Z == MIN_Z == 1
    double hx = r, hy = r;
    double a  = hx - r;
    double bb = hy + r;
    double cos_hx = cos(hx), cos_hy = cos(hy);
    double ca = cos(a),  sa = sin(a);
    double cb = cos(bb), sb = sin(bb);
    double T11 = z * ca / cos_hx;
    double T12 = z * sa / cos_hx;
    double T13 = ((double)W * cos_hx - (double)W * z * ca + 2.0 * tx * z * ca
                  - (double)H * z * sa + 2.0 * ty * z * sa) / (2.0 * cos_hx);
    double T21 = z * sb / cos_hy;
    double T22 = z * cb / cos_hy;
    double T23 = ((double)H * cos_hy - (double)W * z * cb + 2.0 * ty * z * cb
                  - (double)W * z * sb + 2.0 * tx * z * sb) / (2.0 * cos_hy);
    double det = T11 * T22 - T12 * T21;
    p[b * 6 + 0] = (float)( T22 / det);
    p[b * 6 + 1] = (float)(-T12 / det);
    p[b * 6 + 2] = (float)(-T21 / det);
    p[b * 6 + 3] = (float)( T11 / det);
    p[b * 6 + 4] = (float)T13;
    p[b * 6 + 5] = (float)T23;
}

__global__ __launch_bounds__(256) void TCR_warp_kernel(
        const float* __restrict__ img, const float* __restrict__ p,
        float* __restrict__ out, int H, int W,
        int tilesX, int nTile, int nT, int useSwz) {
    __shared__ float lds[MAXROWS * PITCH];

    const int tid = (int)threadIdx.x;
    int i = (int)blockIdx.x;
    int b, t;
    if (useSwz) {   // keep all (channel,tile) blocks of one image on one XCD
        int xcd = i & 7;
        int r   = i >> 3;
        b = xcd + 8 * (r / nT);
        t = r % nT;
    } else {
        b = i / nT;
        t = i % nT;
    }
    const int c  = t / nTile;        // channel
    const int tt = t - c * nTile;    // tile index
    const int tileY = tt / tilesX, tileX = tt - tileY * tilesX;
    const int tx0 = tileX * TW, ty0 = tileY * TH;
    const int tx1 = min(tx0 + TW - 1, W - 1);
    const int ty1 = min(ty0 + TH - 1, H - 1);

    const float i00 = p[b * 6 + 0];
    const float i01 = p[b * 6 + 1];
    const float i10 = p[b * 6 + 2];
    const float i11 = p[b * 6 + 3];
    const float T13 = p[b * 6 + 4];
    const float T23 = p[b * 6 + 5];

    // Unclamped source bbox from the 4 tile corners (affine => corners bound
    // interior; +/-1 margin absorbs fp rounding). Zero-halo: out-of-image
    // positions staged as 0.0f, so the gather loop needs no masks/clamps.
    const float cx0 = (float)tx0 - T13, cx1 = (float)tx1 - T13;
    const float cy0 = (float)ty0 - T23, cy1 = (float)ty1 - T23;
    const float sxA = i00 * cx0 + i01 * cy0, sxB = i00 * cx1 + i01 * cy0;
    const float sxC = i00 * cx0 + i01 * cy1, sxD = i00 * cx1 + i01 * cy1;
    const float syA = i10 * cx0 + i11 * cy0, syB = i10 * cx1 + i11 * cy0;
    const float syC = i10 * cx0 + i11 * cy1, syD = i10 * cx1 + i11 * cy1;
    const float sxmin = fminf(fminf(sxA, sxB), fminf(sxC, sxD));
    const float symin = fminf(fminf(syA, syB), fminf(syC, syD));
    const float symax = fmaxf(fmaxf(syA, syB), fmaxf(syC, syD));
    const int xs0 = ((int)floorf(sxmin) - 1) & ~1;     // even for float2 loads
    const int ys0 = (int)floorf(symin) - 1;
    const int ys1 = min((int)floorf(symax) + 2, ys0 + MAXROWS - 1);
    const int hs = ys1 - ys0 + 1;

    const size_t plane = (size_t)H * W;
    const float* pl = img + (size_t)b * 3 * plane + (size_t)c * plane;

    // --- stage full PITCH-wide rows [ys0, ys1] as float2, zero-halo ---
    {
        const int nPairs = hs * HPITCH;
        for (int j = tid; j < nPairs; j += 256) {
            const int ry = j / HPITCH;
            const int rp = j - ry * HPITCH;
            const int gy = ys0 + ry;
            const int gx = xs0 + 2 * rp;
            // clamped address (always in-bounds), masked values
            const int gyc = min(max(gy, 0), H - 1);
            const int gxc = min(max(gx, 0), W - 2);
            const float2 f = *(const float2*)&pl[(size_t)gyc * W + gxc];
            const bool my  = (unsigned)gy < (unsigned)H;
            const bool mx0 = (unsigned)gx < (unsigned)W;
            const bool mx1 = (unsigned)(gx + 1) < (unsigned)W;
            float2 v;
            v.x = (my & mx0) ? f.x : 0.0f;
            v.y = (my & mx1) ? f.y : 0.0f;
            *(float2*)&lds[2 * j] = v;
        }
    }
    __syncthreads();

    // --- compute: thread (xl = tid&31, yl = tid>>5), 16 row-steps ---
    const int xl = tid & 31;
    const int yl = tid >> 5;
    const int x = tx0 + xl;
    if (x > tx1) return;
    const float dx = (float)x - T13;
    const float sx = i00 * dx;           // i01 == 0 family, but keep general:
    float* po = out + (size_t)b * 3 * plane + (size_t)c * plane;

    #pragma unroll
    for (int k = 0; k < TH / 8; ++k) {
        const int y = ty0 + yl + 8 * k;
        if (y > ty1) break;              // wave-uniform for full tiles
        const float dy = (float)y - T23;
        const float sxk = sx + i01 * dy; // exact reference arithmetic
        const float sy  = i10 * dx + i11 * dy;

        const float x0f = floorf(sxk);
        const float y0f = floorf(sy);
        const float wx = sxk - x0f;
        const float wy = sy - y0f;
        const int x0 = (int)x0f;
        const int y0 = (int)y0f;

        const int iA = (y0 - ys0) * PITCH + (x0 - xs0);
        const float v00 = lds[iA];
        const float v01 = lds[iA + 1];
        const float v10 = lds[iA + PITCH];
        const float v11 = lds[iA + PITCH + 1];

        const float w00 = (1.0f - wx) * (1.0f - wy);
        const float w01 = wx * (1.0f - wy);
        const float w10 = (1.0f - wx) * wy;
        const float w11 = wx * wy;

        const float v = v00 * w00 + v01 * w01 + v10 * w10 + v11 * w11;
        __builtin_nontemporal_store(v, &po[(size_t)y * W + x]);
    }
}

extern "C" void kernel_launch(void* const* d_in, const int* in_sizes, int n_in,
                              void* d_out, int out_size, void* d_ws, size_t ws_size,
                              hipStream_t stream) {
    const float* img = (const float*)d_in[0];
    const float* rnd = (const float*)d_in[1];
    float* out = (float*)d_out;
    float* params = (float*)d_ws;

    const int B = in_sizes[1];            // 128
    const int C = 3;
    const int total = in_sizes[0];        // B*C*H*W
    const int HW = total / (B * C);       // 65536
    int W = 256;                          // square images
    while (W * W > HW) W >>= 1;
    const int H = HW / W;

    TCR_params_kernel<<<(B + 127) / 128, 128, 0, stream>>>(rnd, params, B, W, H);

    const int tilesX = (W + TW - 1) / TW;
    const int tilesY = (H + TH - 1) / TH;
    const int nTile = tilesX * tilesY;    // 16
    const int nT = C * nTile;             // 48 blocks per image
    const int useSwz = (B % 8 == 0) ? 1 : 0;
    dim3 grid(B * nT);
    TCR_warp_kernel<<<grid, 256, 0, stream>>>(img, params, out, H, W,
                                              tilesX, nTile, nT, useSwz);
}